// Round 10
// baseline (506.416 us; speedup 1.0000x reference)
//
#include <hip/hip_runtime.h>
#include <math.h>

#define WDIM 128
#define HDIM 128
#define BDIM 4
#define CDIM 256
#define NROI 2000
#define MPAD 2048
#define FIN  12544   // 256*49
#define FC   1024
#define HWC  (HDIM * WDIM * CDIM)

typedef unsigned short bf16r;
typedef unsigned short u16;
typedef __attribute__((ext_vector_type(8))) short bf16x8;   // 8 bf16 = 4 VGPRs
typedef __attribute__((ext_vector_type(4))) float f32x4;
typedef __attribute__((ext_vector_type(8))) _Float16 half8;
typedef __attribute__((ext_vector_type(8))) unsigned short ushort8v;

__device__ __forceinline__ bf16r f2bf(float f) {
    unsigned u = __float_as_uint(f);
    u += 0x7FFFu + ((u >> 16) & 1u);
    return (bf16r)(u >> 16);
}
__device__ __forceinline__ float bf2f(bf16r h) {
    return __uint_as_float(((unsigned)h) << 16);
}
__device__ __forceinline__ u16 f2h(float f) {
    union { u16 s; _Float16 h; } c; c.h = (_Float16)f; return c.s;
}

__device__ __forceinline__ void async16(const bf16r* g, bf16r* l) {
    __builtin_amdgcn_global_load_lds(
        (const __attribute__((address_space(1))) unsigned int*)g,
        (__attribute__((address_space(3))) unsigned int*)l, 16, 0, 0);
}

#define VMW(n) asm volatile("s_waitcnt vmcnt(" #n ")" ::: "memory")
#define BARRIER() __builtin_amdgcn_s_barrier()

__device__ __forceinline__ void roi_geom(const float* __restrict__ rois, int n,
                                         int& b, float& sw, float& sh,
                                         float& rw, float& rh) {
    const float* r = rois + (size_t)n * 5;
    b = (int)r[0];
    float r1 = floorf(r[1] + 0.5f);
    float r2 = floorf(r[2] + 0.5f);
    float r3 = floorf(r[3] + 0.5f);
    float r4 = floorf(r[4] + 0.5f);
    sw = r1 * 0.0625f - 0.5f;
    sh = r2 * 0.0625f - 0.5f;
    float ew = (r3 + 1.0f) * 0.0625f - 0.5f;
    float eh = (r4 + 1.0f) * 0.0625f - 0.5f;
    rw = fmaxf(ew - sw, 0.1f);
    rh = fmaxf(eh - sh, 0.1f);
}

// ---- separable geometry phase --------------------------------------------
__device__ __forceinline__ void build_geometry(
        int n, int tid, const float* __restrict__ rois,
        const float* __restrict__ offs,      // null for pass 1
        const float* __restrict__ maskb,     // null for pass 1
        float* axW, unsigned* axMeta, uint2* wpix, int* npx, float* scale) {
    if (tid < 98) {
        int po = tid >> 1, axis = tid & 1;
        int b; float sw, sh, rw, rh;
        roi_geom(rois, n, b, sw, sh, rw, rh);
        float bw = rw * (1.f / 7.f), bh = rh * (1.f / 7.f);
        int ph = po / 7, pw = po - ph * 7;
        float start, sub;
        if (axis == 0) {
            start = (float)pw * bw + sw;
            if (offs) start += offs[(size_t)n * 98 + po] * 0.1f * rw;
            sub = bw * 0.25f;
        } else {
            start = (float)ph * bh + sh;
            if (offs) start += offs[(size_t)n * 98 + 49 + po] * 0.1f * rh;
            sub = bh * 0.25f;
        }
        float wsl[5] = {0.f, 0.f, 0.f, 0.f, 0.f};
        int base = 0, cnt = 0, mx = 0, any = 0;
#pragma unroll
        for (int i = 0; i < 4; ++i) {
            float p = start + (float)i * sub;
            bool valid = (p >= -0.5f) & (p <= 127.5f);
            float pc = fminf(fmaxf(p, 0.f), 127.f);
            int p0 = (int)floorf(pc);
            float d = pc - (float)p0;
            int p1 = min(p0 + 1, 127);
            if (valid) {
                if (!any) { base = p0; any = 1; }
                int c0 = p0 - base, c1 = p1 - base;
                float w0 = 1.f - d;
#pragma unroll
                for (int k = 0; k < 5; ++k)
                    wsl[k] += ((c0 == k) ? w0 : 0.f) + ((c1 == k) ? d : 0.f);
                cnt++;
                mx = max(mx, c1);
            }
        }
        int N = any ? mx + 1 : 0;
        axMeta[tid] = (unsigned)(N | (cnt << 3) | (base << 6));
#pragma unroll
        for (int k = 0; k < 5; ++k) axW[tid * 5 + k] = wsl[k];
    }
    __syncthreads();
    if (tid < 245) {
        int po = tid / 5, r = tid - po * 5;
        unsigned mx_ = axMeta[po * 2], my_ = axMeta[po * 2 + 1];
        int NX = mx_ & 7, NY = my_ & 7;
        int bx = (mx_ >> 6) & 127, by = (my_ >> 6) & 127;
        if (r == 0) {
            int cntx = (mx_ >> 3) & 7, cnty = (my_ >> 3) & 7;
            int ct = cntx * cnty;
            float sc = (ct > 0) ? 1.f / (float)ct : 0.f;
            if (maskb) sc *= (ct > 0) ? maskb[(size_t)n * 49 + po] : 0.f;
            npx[po] = NX * NY;
            scale[po] = sc;
        }
        if (r < NY) {
            float wyr = axW[(po * 2 + 1) * 5 + r];
            unsigned rowoff = (unsigned)(((by + r) * 128 + bx) * 512);  // bytes
#pragma unroll
            for (int c = 0; c < 5; ++c)
                if (c < NX)
                    wpix[po * 28 + r * NX + c] =
                        make_uint2(rowoff + (unsigned)c * 512u,
                                   __float_as_uint(wyr * axW[po * 2 * 5 + c]));
        }
    }
    __syncthreads();
}

// Fused prep: 4 weight transposes (fp32 -> bf16, Bt[n][k]) + data transpose
// ([B,C,H,W] fp32 -> [B,H,W,C] fp16) as segments of one grid.
__device__ __forceinline__ void conv_body(const float* __restrict__ srcA,
                                          const float* __restrict__ srcB,
                                          int nsplit, int ncols, int Nout, int K,
                                          int kb, int nb, bf16r* __restrict__ dst,
                                          float (*t)[33], int tid) {
    int k0 = kb << 5, n0 = nb << 5;
    int tx = tid & 31, ty = tid >> 5;
#pragma unroll
    for (int i = 0; i < 32; i += 8) {
        int k = k0 + ty + i;
        int n = n0 + tx;
        const float* s = (n < nsplit) ? srcA : srcB;
        int col = (n < nsplit) ? n : n - nsplit;
        float v = (n < Nout && col < ncols) ? s[(size_t)k * ncols + col] : 0.f;
        t[ty + i][tx] = v;
    }
    __syncthreads();
#pragma unroll
    for (int i = 0; i < 32; i += 8) {
        int n = n0 + ty + i;
        if (n < Nout) dst[(size_t)n * K + k0 + tx] = f2bf(t[tx][ty + i]);
    }
}

__global__ __launch_bounds__(256) void prep_kernel(
        const float* __restrict__ w1, const float* __restrict__ mw1,
        const float* __restrict__ w2, const float* __restrict__ w3,
        const float* __restrict__ mw2,
        bf16r* __restrict__ bt1, bf16r* __restrict__ bt2,
        bf16r* __restrict__ bt3, bf16r* __restrict__ bt4,
        const float* __restrict__ data, u16* __restrict__ data_t) {
    __shared__ float t[32][33];
    int tid = threadIdx.x;
    int blk = blockIdx.x;
    if (blk < 25088) {            // bt1: K=FIN, Nout=2048 (w1|mw1)
        conv_body(w1, mw1, 1024, 1024, 2048, FIN, blk % 392, blk / 392, bt1, t, tid);
        return;
    }
    blk -= 25088;
    if (blk < 1024) {             // bt2: K=1024, Nout=1024
        conv_body(w2, w2, 1 << 30, 1024, 1024, 1024, blk & 31, blk >> 5, bt2, t, tid);
        return;
    }
    blk -= 1024;
    if (blk < 128) {              // bt3: K=1024, Nout=98
        conv_body(w3, w3, 1 << 30, 98, 98, 1024, blk & 31, blk >> 5, bt3, t, tid);
        return;
    }
    blk -= 128;
    if (blk < 64) {               // bt4: K=1024, Nout=49
        conv_body(mw2, mw2, 1 << 30, 49, 49, 1024, blk & 31, blk >> 5, bt4, t, tid);
        return;
    }
    blk -= 64;
    {                             // data transpose: 4 x 8 x 512 blocks
        int x0 = (blk & 3) << 5;
        int c0 = ((blk >> 2) & 7) << 5;
        int bz = blk >> 5;
        int b = bz >> 7, y = bz & 127;
        int tx = tid & 31, ty = tid >> 5;
#pragma unroll
        for (int i = 0; i < 32; i += 8)
            t[ty + i][tx] = data[(((size_t)b * CDIM + c0 + ty + i) * HDIM + y) * WDIM + x0 + tx];
        __syncthreads();
#pragma unroll
        for (int i = 0; i < 32; i += 8)
            data_t[(((size_t)b * HDIM + y) * WDIM + x0 + ty + i) * CDIM + c0 + tx] = f2h(t[tx][ty + i]);
    }
}

// Pass-1 pooling: one block per ROI, 256 ch. Each 32-lane half owns one po;
// lane = 8 fp16 channels. Output xf in w1-natural k-order (k=c*49+po).
__global__ __launch_bounds__(512) void pool1_kernel(const u16* __restrict__ data_t,
                                                    const float* __restrict__ rois,
                                                    bf16r* __restrict__ xf) {
    __shared__ ushort tileX[49][264];   // 25,872 B
    __shared__ float axW[98 * 5];
    __shared__ unsigned axMeta[98];
    __shared__ uint2 wpix[49 * 28];
    __shared__ int npx[49];
    __shared__ float scale[49];
    int n = blockIdx.x, tid = threadIdx.x;
    build_geometry(n, tid, rois, nullptr, nullptr, axW, axMeta, wpix, npx, scale);
    int b = (int)rois[(size_t)n * 5];
    int wave = tid >> 6, lane = tid & 63, shalf = lane >> 5, c8 = (lane & 31) << 3;
    const char* dpb = (const char*)(data_t + (size_t)b * HWC + c8);
    for (int po = wave * 2 + shalf; po < 49; po += 16) {
        int npe = npx[po];
        float sc = scale[po];
        const uint2* wp = wpix + po * 28;
        float a[8];
#pragma unroll
        for (int k = 0; k < 8; ++k) a[k] = 0.f;
        int p = 0;
        for (; p + 2 <= npe; p += 2) {
            uint2 q0 = wp[p], q1 = wp[p + 1];
            half8 v0 = *(const half8*)(dpb + q0.x);
            half8 v1 = *(const half8*)(dpb + q1.x);
            float w0 = __uint_as_float(q0.y), w1 = __uint_as_float(q1.y);
#pragma unroll
            for (int k = 0; k < 8; ++k) a[k] += w0 * (float)v0[k];
#pragma unroll
            for (int k = 0; k < 8; ++k) a[k] += w1 * (float)v1[k];
        }
        if (p < npe) {
            uint2 q0 = wp[p];
            half8 v0 = *(const half8*)(dpb + q0.x);
            float w0 = __uint_as_float(q0.y);
#pragma unroll
            for (int k = 0; k < 8; ++k) a[k] += w0 * (float)v0[k];
        }
        ushort8v o;
#pragma unroll
        for (int k = 0; k < 8; ++k) o[k] = f2bf(a[k] * sc);
        *(ushort8v*)&tileX[po][c8] = o;
    }
    __syncthreads();
    bf16r* xp = xf + (size_t)n * FIN;
    for (int u = tid; u < 3136; u += 512) {
        int k0 = u << 2;
        ushort4 o;
#pragma unroll
        for (int j = 0; j < 4; ++j) {
            int k = k0 + j;
            int c = k / 49;
            int po = k - c * 49;
            ((ushort*)&o)[j] = tileX[po][c];
        }
        *(ushort4*)(xp + k0) = o;
    }
}

// Pass-2 pooling with offsets, times mask. 2 blocks/ROI (128 ch each),
// each 16-lane quarter owns one po. XOR-swizzled f32 LDS tile for the
// coalesced [c*49+po] writeout.
__global__ __launch_bounds__(512) void pool2_kernel(const u16* __restrict__ data_t,
                                                    const float* __restrict__ rois,
                                                    const float* __restrict__ offs,
                                                    const float* __restrict__ maskb,
                                                    float* __restrict__ out) {
    __shared__ float tile[49 * 128];   // 25,088 B
    __shared__ float axW[98 * 5];
    __shared__ unsigned axMeta[98];
    __shared__ uint2 wpix[49 * 28];
    __shared__ int npx[49];
    __shared__ float scale[49];
    int n = blockIdx.x, chalf = blockIdx.y, tid = threadIdx.x;
    build_geometry(n, tid, rois, offs, maskb, axW, axMeta, wpix, npx, scale);
    int b = (int)rois[(size_t)n * 5];
    int wave = tid >> 6, lane = tid & 63, q = lane >> 4, c8 = (lane & 15) << 3;
    const char* dpb = (const char*)(data_t + (size_t)b * HWC + chalf * 128 + c8);
    for (int po = wave * 4 + q; po < 49; po += 32) {
        int npe = npx[po];
        float sc = scale[po];
        const uint2* wp = wpix + po * 28;
        float a[8];
#pragma unroll
        for (int k = 0; k < 8; ++k) a[k] = 0.f;
        int p = 0;
        for (; p + 2 <= npe; p += 2) {
            uint2 q0 = wp[p], q1 = wp[p + 1];
            half8 v0 = *(const half8*)(dpb + q0.x);
            half8 v1 = *(const half8*)(dpb + q1.x);
            float w0 = __uint_as_float(q0.y), w1 = __uint_as_float(q1.y);
#pragma unroll
            for (int k = 0; k < 8; ++k) a[k] += w0 * (float)v0[k];
#pragma unroll
            for (int k = 0; k < 8; ++k) a[k] += w1 * (float)v1[k];
        }
        if (p < npe) {
            uint2 q0 = wp[p];
            half8 v0 = *(const half8*)(dpb + q0.x);
            float w0 = __uint_as_float(q0.y);
#pragma unroll
            for (int k = 0; k < 8; ++k) a[k] += w0 * (float)v0[k];
        }
        int cs = c8 ^ ((po & 7) << 3);
        float4 lo = make_float4(a[0] * sc, a[1] * sc, a[2] * sc, a[3] * sc);
        float4 hi = make_float4(a[4] * sc, a[5] * sc, a[6] * sc, a[7] * sc);
        *(float4*)&tile[po * 128 + cs] = lo;
        *(float4*)&tile[po * 128 + cs + 4] = hi;
    }
    __syncthreads();
    float* op = out + (size_t)n * FIN + (size_t)chalf * 6272;
    for (int i = tid; i < 6272; i += 512) {
        int c = i / 49, po = i - c * 49;
        op[i] = tile[po * 128 + (c ^ ((po & 7) << 3))];
    }
}

// =====================================================================
// 256x256 / BK=64 / 8-wave / 8-phase counted-vmcnt GEMM; bf16 partials.
// Register-persistent fragments; R4-verified schedule. ktiles = K/64.
// =====================================================================
#define STAGE_A(buf, h, kt) do { \
    async16(Abase + (size_t)(kt) * 64 + sAoff[h][0], &lds[buf][0][((h) * 128 + wave * 8) * 64]); \
    async16(Abase + (size_t)(kt) * 64 + sAoff[h][1], &lds[buf][0][((h) * 128 + 64 + wave * 8) * 64]); \
} while (0)
#define STAGE_B(buf, h, kt) do { \
    async16(Bbase + (size_t)(kt) * 64 + sBoff[h][0], &lds[buf][1][((h) * 128 + wave * 8) * 64]); \
    async16(Bbase + (size_t)(kt) * 64 + sBoff[h][1], &lds[buf][1][((h) * 128 + 64 + wave * 8) * 64]); \
} while (0)
#define LDA_HALF(buf, mh) do { \
    const char* Ar = (const char*)&lds[buf][0][0] + aQ + (mh) * 16384; \
    _Pragma("unroll") for (int i = 0; i < 4; ++i) \
        _Pragma("unroll") for (int ks = 0; ks < 2; ++ks) \
            aF[i][ks] = *(const bf16x8*)(Ar + i * 2048 + fRB[ks]); \
} while (0)
#define LDB_HALF(dst, buf, nh) do { \
    const char* Br = (const char*)&lds[buf][1][0] + bQ + (nh) * 16384; \
    _Pragma("unroll") for (int jf = 0; jf < 2; ++jf) \
        _Pragma("unroll") for (int ks = 0; ks < 2; ++ks) \
            dst[jf][ks] = *(const bf16x8*)(Br + jf * 2048 + fRB[ks]); \
} while (0)
#define MMA_Q(mh, nh, B) do { \
    __builtin_amdgcn_s_setprio(1); \
    _Pragma("unroll") for (int i = 0; i < 4; ++i) \
        _Pragma("unroll") for (int jf = 0; jf < 2; ++jf) \
            _Pragma("unroll") for (int ks = 0; ks < 2; ++ks) \
                acc[(mh) * 4 + i][(nh) * 2 + jf] = __builtin_amdgcn_mfma_f32_16x16x32_bf16( \
                    aF[i][ks], B[jf][ks], acc[(mh) * 4 + i][(nh) * 2 + jf], 0, 0, 0); \
    __builtin_amdgcn_s_setprio(0); \
} while (0)

__global__ __launch_bounds__(512, 2) void gemm256_kernel(
        const bf16r* __restrict__ A, int lda,
        const bf16r* __restrict__ Bt, int ldb,
        bf16r* __restrict__ P, int Npad, int KS, int ktiles) {
    __shared__ bf16r lds[2][2][256 * 64];   // 128 KiB
    int tid = threadIdx.x;
    int wave = tid >> 6, lane = tid & 63;
    int l15 = lane & 15, quad = lane >> 4;
    int wm = wave >> 2, wn = wave & 3;

    // within-z bijective XCD swizzle (gridDim.x*gridDim.y % 8 == 0)
    int idx = blockIdx.x + gridDim.x * blockIdx.y;
    int nid = (idx & 7) * ((gridDim.x * gridDim.y) >> 3) + (idx >> 3);
    int bx = nid % gridDim.x, by = nid / gridDim.x;
    int m0 = by << 8, n0 = bx << 8;
    int z = blockIdx.z;

    // staging source offsets (pre-swizzled granule)
    int sAoff[2][2], sBoff[2][2];
#pragma unroll
    for (int h = 0; h < 2; ++h)
#pragma unroll
        for (int j = 0; j < 2; ++j) {
            int slot = h * 128 + j * 64 + wave * 8 + (lane >> 3);
            int g = (lane & 7) ^ ((slot >> 1) & 7);
            int rowA = ((slot >> 6) & 1) * 128 + (slot >> 7) * 64 + (slot & 63);
            int colB = ((slot >> 5) & 3) * 64 + (slot >> 7) * 32 + (slot & 31);
            sAoff[h][j] = rowA * lda + g * 8;
            sBoff[h][j] = colB * ldb + g * 8;
        }
    const bf16r* Abase = A + (size_t)m0 * lda;
    const bf16r* Bbase = Bt + (size_t)n0 * ldb;

    // frag-read per-lane byte bases (granule XOR keyed on l15 bits [3:1])
    int fRB[2];
#pragma unroll
    for (int ks = 0; ks < 2; ++ks)
        fRB[ks] = l15 * 128 + ((((ks << 2) + quad) ^ ((l15 >> 1) & 7)) << 4);
    int aQ = wm * 8192;    // wm*64 slots * 128 B
    int bQ = wn * 4096;    // wn*32 slots * 128 B

    f32x4 acc[8][4];
#pragma unroll
    for (int i = 0; i < 8; ++i)
#pragma unroll
        for (int j = 0; j < 4; ++j) acc[i][j] = (f32x4){0.f, 0.f, 0.f, 0.f};
    bf16x8 aF[4][2], bF0[2][2], bF1[2][2];

    int tb = ((ktiles * z) / KS) & ~1;
    int te = (z == KS - 1) ? ktiles : ((ktiles * (z + 1)) / KS) & ~1;
    int nit = (te - tb) >> 1;

    // prologue: tile tb fully into buf0; tile tb+1 halves A0,B0 into buf1
    STAGE_A(0, 0, tb); STAGE_B(0, 0, tb); STAGE_A(0, 1, tb); STAGE_B(0, 1, tb);
    STAGE_A(1, 0, tb + 1); STAGE_B(1, 0, tb + 1);
    VMW(4);
    BARRIER();

    for (int it = 0; it < nit; ++it) {
        int t1 = tb + 2 * it + 1, nx0 = t1 + 1, nx1 = t1 + 2;
        bool last = (it == nit - 1);
        // ---- buf0 (K-tile 2t): quadrants (0,0)(0,1)(1,1)(1,0) ----
        LDA_HALF(0, 0); LDB_HALF(bF0, 0, 0);
        STAGE_A(1, 1, t1);
        BARRIER();
        MMA_Q(0, 0, bF0);
        BARRIER();

        LDB_HALF(bF1, 0, 1);
        STAGE_B(1, 1, t1);
        BARRIER();
        MMA_Q(0, 1, bF1);
        BARRIER();

        LDA_HALF(0, 1);
        if (!last) STAGE_A(0, 0, nx0);
        BARRIER();
        MMA_Q(1, 1, bF1);
        BARRIER();

        if (!last) STAGE_B(0, 0, nx0);
        BARRIER();
        MMA_Q(1, 0, bF0);
        if (last) { VMW(0); } else { VMW(4); }
        BARRIER();

        // ---- buf1 (K-tile 2t+1) ----
        LDA_HALF(1, 0); LDB_HALF(bF0, 1, 0);
        if (!last) STAGE_A(0, 1, nx0);
        BARRIER();
        MMA_Q(0, 0, bF0);
        BARRIER();

        LDB_HALF(bF1, 1, 1);
        if (!last) STAGE_B(0, 1, nx0);
        BARRIER();
        MMA_Q(0, 1, bF1);
        BARRIER();

        LDA_HALF(1, 1);
        if (!last) STAGE_A(1, 0, nx1);
        BARRIER();
        MMA_Q(1, 1, bF1);
        BARRIER();

        if (!last) STAGE_B(1, 0, nx1);
        BARRIER();
        MMA_Q(1, 0, bF0);
        if (!last) { VMW(4); }
        BARRIER();
    }

    bf16r* Pp = P + (size_t)z * MPAD * Npad;
#pragma unroll
    for (int I = 0; I < 8; ++I) {
        int row = m0 + wm * 128 + I * 16 + quad * 4;
#pragma unroll
        for (int J = 0; J < 4; ++J) {
            int col = n0 + wn * 64 + J * 16 + l15;
            bf16r* o = Pp + (size_t)row * Npad + col;
#pragma unroll
            for (int r = 0; r < 4; ++r) o[(size_t)r * Npad] = f2bf(acc[I][J][r]);
        }
    }
}

// MFMA bf16 GEMM (128x128 2-barrier, split-K, f32 partials): fallback GEMM1.
__global__ __launch_bounds__(256) void gemm_mfma_kernel(
        const bf16r* __restrict__ A, int lda,
        const bf16r* __restrict__ Bt, int K,
        float* __restrict__ P, int Npad, int KS) {
    __shared__ bf16r As[128 * 32];
    __shared__ bf16r Bs[128 * 32];
    int tid = threadIdx.x;
    int wave = tid >> 6, lane = tid & 63;
    int nwgxy = gridDim.x * gridDim.y;
    int idx = blockIdx.x + gridDim.x * blockIdx.y;
    int chunk = nwgxy >> 3;
    int nid = (idx & 7) * chunk + (idx >> 3);
    int bx = nid % gridDim.x, by = nid / gridDim.x;
    int m0 = by << 7, n0 = bx << 7;
    int z = blockIdx.z;

    int srow = lane >> 2;
    int kchunk = ((lane & 3) ^ ((lane >> 3) & 3)) << 3;
    const bf16r* aG0 = A + (size_t)(m0 + wave * 32 + srow) * lda + kchunk;
    const bf16r* aG1 = A + (size_t)(m0 + wave * 32 + 16 + srow) * lda + kchunk;
    const bf16r* bG0 = Bt + (size_t)(n0 + wave * 32 + srow) * K + kchunk;
    const bf16r* bG1 = Bt + (size_t)(n0 + wave * 32 + 16 + srow) * K + kchunk;
    bf16r* aL0 = As + wave * 1024;
    bf16r* aL1 = As + wave * 1024 + 512;
    bf16r* bL0 = Bs + wave * 1024;
    bf16r* bL1 = Bs + wave * 1024 + 512;

    int l15 = lane & 15, quad = lane >> 4;
    int wr = wave >> 1, wc = wave & 1;
    int psw = (quad ^ ((l15 >> 1) & 3)) << 3;
    int aoff[4], boff[4];
#pragma unroll
    for (int t = 0; t < 4; ++t) {
        aoff[t] = ((wr * 64 + t * 16 + l15) * 32 + psw) * 2;
        boff[t] = ((wc * 64 + t * 16 + l15) * 32 + psw) * 2;
    }

    f32x4 acc[4][4];
#pragma unroll
    for (int i = 0; i < 4; ++i)
#pragma unroll
        for (int j = 0; j < 4; ++j) acc[i][j] = (f32x4){0.f, 0.f, 0.f, 0.f};

    int iters = K >> 5;
    int i0 = (int)((long)iters * z / KS);
    int i1 = (int)((long)iters * (z + 1) / KS);

    {
        size_t k0 = (size_t)i0 << 5;
        async16(aG0 + k0, aL0); async16(aG1 + k0, aL1);
        async16(bG0 + k0, bL0); async16(bG1 + k0, bL1);
    }
    for (int it = i0; it < i1; ++it) {
        __syncthreads();
        bf16x8 af[4], bfv[4];
#pragma unroll
        for (int t = 0; t < 4; ++t) af[t] = *(const bf16x8*)((const char*)As + aoff[t]);
#pragma unroll
        for (int t = 0; t < 4; ++t) bfv[t] = *(const bf16x8*)((const char*)Bs + boff[t]);
        __syncthreads();
        if (it + 1 < i1) {
            size_t k0 = (size_t)(it + 1) << 5;
            async16(aG0 + k0, aL0); async16(aG1 + k0, aL1);
            async16(bG0 + k0, bL0); async16(bG1 + k0, bL1);
        }
#pragma unroll
        for (int i = 0; i < 4; ++i)
#pragma unroll
            for (int j = 0; j < 4; ++j)
                acc[i][j] = __builtin_amdgcn_mfma_f32_16x16x32_bf16(af[i], bfv[j], acc[i][j], 0, 0, 0);
    }

    float* Pp = P + (size_t)z * MPAD * Npad;
#pragma unroll
    for (int i = 0; i < 4; ++i) {
        int row = m0 + wr * 64 + i * 16 + quad * 4;
#pragma unroll
        for (int j = 0; j < 4; ++j) {
            int col = n0 + wc * 64 + j * 16 + l15;
            float* o = Pp + (size_t)row * Npad + col;
#pragma unroll
            for (int r = 0; r < 4; ++r) o[(size_t)r * Npad] = acc[i][j][r];
        }
    }
}

// GEMM2 fused: h2 = relu(hm[:, :1024] @ w2 + b2) as bf16. 128x128 tile,
// KS=1 (full K=1024 in fp32 accumulators — strictly better precision than
// the split-K+reduce path it replaces). Grid (8,16).
__global__ __launch_bounds__(256) void gemm2f_kernel(
        const bf16r* __restrict__ A, int lda,
        const bf16r* __restrict__ Bt,
        const float* __restrict__ bias,
        bf16r* __restrict__ Out) {
    __shared__ bf16r As[128 * 32];
    __shared__ bf16r Bs[128 * 32];
    const int K = 1024;
    int tid = threadIdx.x;
    int wave = tid >> 6, lane = tid & 63;
    int nwgxy = gridDim.x * gridDim.y;
    int idx = blockIdx.x + gridDim.x * blockIdx.y;
    int nid = (idx & 7) * (nwgxy >> 3) + (idx >> 3);
    int bx = nid % gridDim.x, by = nid / gridDim.x;
    int m0 = by << 7, n0 = bx << 7;

    int srow = lane >> 2;
    int kchunk = ((lane & 3) ^ ((lane >> 3) & 3)) << 3;
    const bf16r* aG0 = A + (size_t)(m0 + wave * 32 + srow) * lda + kchunk;
    const bf16r* aG1 = A + (size_t)(m0 + wave * 32 + 16 + srow) * lda + kchunk;
    const bf16r* bG0 = Bt + (size_t)(n0 + wave * 32 + srow) * K + kchunk;
    const bf16r* bG1 = Bt + (size_t)(n0 + wave * 32 + 16 + srow) * K + kchunk;
    bf16r* aL0 = As + wave * 1024;
    bf16r* aL1 = As + wave * 1024 + 512;
    bf16r* bL0 = Bs + wave * 1024;
    bf16r* bL1 = Bs + wave * 1024 + 512;

    int l15 = lane & 15, quad = lane >> 4;
    int wr = wave >> 1, wc = wave & 1;
    int psw = (quad ^ ((l15 >> 1) & 3)) << 3;
    int aoff[4], boff[4];
#pragma unroll
    for (int t = 0; t < 4; ++t) {
        aoff[t] = ((wr * 64 + t * 16 + l15) * 32 + psw) * 2;
        boff[t] = ((wc * 64 + t * 16 + l15) * 32 + psw) * 2;
    }

    f32x4 acc[4][4];
#pragma unroll
    for (int i = 0; i < 4; ++i)
#pragma unroll
        for (int j = 0; j < 4; ++j) acc[i][j] = (f32x4){0.f, 0.f, 0.f, 0.f};

    {
        async16(aG0, aL0); async16(aG1, aL1);
        async16(bG0, bL0); async16(bG1, bL1);
    }
    for (int it = 0; it < 32; ++it) {
        __syncthreads();
        bf16x8 af[4], bfv[4];
#pragma unroll
        for (int t = 0; t < 4; ++t) af[t] = *(const bf16x8*)((const char*)As + aoff[t]);
#pragma unroll
        for (int t = 0; t < 4; ++t) bfv[t] = *(const bf16x8*)((const char*)Bs + boff[t]);
        __syncthreads();
        if (it + 1 < 32) {
            size_t k0 = (size_t)(it + 1) << 5;
            async16(aG0 + k0, aL0); async16(aG1 + k0, aL1);
            async16(bG0 + k0, bL0); async16(bG1 + k0, bL1);
        }
#pragma unroll
        for (int i = 0; i < 4; ++i)
#pragma unroll
            for (int j = 0; j < 4; ++j)
                acc[i][j] = __builtin_amdgcn_mfma_f32_16x16x32_bf16(af[i], bfv[j], acc[i][j], 0, 0, 0);
    }

#pragma unroll
    for (int i = 0; i < 4; ++i) {
        int row = m0 + wr * 64 + i * 16 + quad * 4;
#pragma unroll
        for (int j = 0; j < 4; ++j) {
            int col = n0 + wc * 64 + j * 16 + l15;
            float b = bias[col];
#pragma unroll
            for (int r = 0; r < 4; ++r)
                Out[(size_t)(row + r) * 1024 + col] = f2bf(fmaxf(acc[i][j][r] + b, 0.f));
        }
    }
}

// Fused tail GEMMs + epilogues, KS=1. blockIdx.y: [0,16) prob0 (offs =
// h2 @ w3t + b3, fp32, 98 cols), [16,32) prob1 (maskb = sigmoid(hm[:,1024:]
// @ mw2t + mb2), 49 cols). Stores guarded row<NROI & col<N.
__global__ __launch_bounds__(256) void tailf_kernel(
        const bf16r* __restrict__ A0, int lda0,
        const bf16r* __restrict__ A1, int lda1,
        const bf16r* __restrict__ Bt0, const bf16r* __restrict__ Bt1,
        const float* __restrict__ b3, const float* __restrict__ mb2,
        float* __restrict__ offs, float* __restrict__ maskb) {
    __shared__ bf16r As[128 * 32];
    __shared__ bf16r Bs[128 * 32];
    const int K = 1024;
    int tid = threadIdx.x;
    int wave = tid >> 6, lane = tid & 63;
    int prob = blockIdx.y >> 4;
    int m0 = (blockIdx.y & 15) << 7;
    const bf16r* A = prob ? A1 : A0;
    int lda = prob ? lda1 : lda0;
    const bf16r* Bt = prob ? Bt1 : Bt0;

    int srow = lane >> 2;
    int kchunk = ((lane & 3) ^ ((lane >> 3) & 3)) << 3;
    const bf16r* aG0 = A + (size_t)(m0 + wave * 32 + srow) * lda + kchunk;
    const bf16r* aG1 = A + (size_t)(m0 + wave * 32 + 16 + srow) * lda + kchunk;
    const bf16r* bG0 = Bt + (size_t)(wave * 32 + srow) * K + kchunk;
    const bf16r* bG1 = Bt + (size_t)(wave * 32 + 16 + srow) * K + kchunk;
    bf16r* aL0 = As + wave * 1024;
    bf16r* aL1 = As + wave * 1024 + 512;
    bf16r* bL0 = Bs + wave * 1024;
    bf16r* bL1 = Bs + wave * 1024 + 512;

    int l15 = lane & 15, quad = lane >> 4;
    int wr = wave >> 1, wc = wave & 1;
    int psw = (quad ^ ((l15 >> 1) & 3)) << 3;
    int aoff[4], boff[4];
#pragma unroll
    for (int t = 0; t < 4; ++t) {
        aoff[t] = ((wr * 64 + t * 16 + l15) * 32 + psw) * 2;
        boff[t] = ((wc * 64 + t * 16 + l15) * 32 + psw) * 2;
    }

    f32x4 acc[4][4];
#pragma unroll
    for (int i = 0; i < 4; ++i)
#pragma unroll
        for (int j = 0; j < 4; ++j) acc[i][j] = (f32x4){0.f, 0.f, 0.f, 0.f};

    {
        async16(aG0, aL0); async16(aG1, aL1);
        async16(bG0, bL0); async16(bG1, bL1);
    }
    for (int it = 0; it < 32; ++it) {
        __syncthreads();
        bf16x8 af[4], bfv[4];
#pragma unroll
        for (int t = 0; t < 4; ++t) af[t] = *(const bf16x8*)((const char*)As + aoff[t]);
#pragma unroll
        for (int t = 0; t < 4; ++t) bfv[t] = *(const bf16x8*)((const char*)Bs + boff[t]);
        __syncthreads();
        if (it + 1 < 32) {
            size_t k0 = (size_t)(it + 1) << 5;
            async16(aG0 + k0, aL0); async16(aG1 + k0, aL1);
            async16(bG0 + k0, bL0); async16(bG1 + k0, bL1);
        }
#pragma unroll
        for (int i = 0; i < 4; ++i)
#pragma unroll
            for (int j = 0; j < 4; ++j)
                acc[i][j] = __builtin_amdgcn_mfma_f32_16x16x32_bf16(af[i], bfv[j], acc[i][j], 0, 0, 0);
    }

#pragma unroll
    for (int i = 0; i < 4; ++i) {
        int row = m0 + wr * 64 + i * 16 + quad * 4;
#pragma unroll
        for (int j = 0; j < 4; ++j) {
            int col = wc * 64 + j * 16 + l15;
#pragma unroll
            for (int r = 0; r < 4; ++r) {
                int rr = row + r;
                if (rr < NROI) {
                    if (prob == 0) {
                        if (col < 98) offs[(size_t)rr * 98 + col] = acc[i][j][r] + b3[col];
                    } else {
                        if (col < 49)
                            maskb[(size_t)rr * 49 + col] =
                                1.f / (1.f + expf(-(acc[i][j][r] + mb2[col])));
                    }
                }
            }
        }
    }
}

// sum split-K partials + bias + activation + dtype convert (float4/thread).
// pbf16: partials stored as bf16 (gemm256 path).
__global__ __launch_bounds__(256) void reduce_kernel(
        const void* __restrict__ Pv, int shift, int KS, int pbf16,
        const float* __restrict__ bias0, const float* __restrict__ bias1, int bsplit,
        void* __restrict__ Out, int ldo, int M, int Nreal, int outmode) {
    int idx = (blockIdx.x * 256 + threadIdx.x) << 2;
    int Npad = 1 << shift;
    int row = idx >> shift, col = idx & (Npad - 1);
    f32x4 s = (f32x4){0.f, 0.f, 0.f, 0.f};
    size_t plane = (size_t)MPAD << shift;
    if (pbf16) {
        const bf16r* P = (const bf16r*)Pv;
        for (int zz = 0; zz < KS; ++zz) {
            ushort4 u = *(const ushort4*)(P + (size_t)zz * plane + idx);
            s[0] += bf2f(u.x); s[1] += bf2f(u.y); s[2] += bf2f(u.z); s[3] += bf2f(u.w);
        }
    } else {
        const float* P = (const float*)Pv;
        for (int zz = 0; zz < KS; ++zz) s += *(const f32x4*)(P + (size_t)zz * plane + idx);
    }
    if (row < M) {
#pragma unroll
        for (int e = 0; e < 4; ++e) {
            int c = col + e;
            if (c < Nreal) {
                float b = (c < bsplit) ? bias0[c] : bias1[c - bsplit];
                float v = s[e] + b;
                if (outmode == 0) {
                    v = fmaxf(v, 0.f);
                    ((bf16r*)Out)[(size_t)row * ldo + c] = f2bf(v);
                } else {
                    if (outmode == 2) v = 1.f / (1.f + expf(-v));
                    ((float*)Out)[(size_t)row * ldo + c] = v;
                }
            }
        }
    }
}

extern "C" void kernel_launch(void* const* d_in, const int* in_sizes, int n_in,
                              void* d_out, int out_size, void* d_ws, size_t ws_size,
                              hipStream_t stream) {
    const float* data = (const float*)d_in[0];
    const float* rois = (const float*)d_in[1];
    const float* w1   = (const float*)d_in[2];
    const float* b1   = (const float*)d_in[3];
    const float* w2   = (const float*)d_in[4];
    const float* b2   = (const float*)d_in[5];
    const float* w3   = (const float*)d_in[6];
    const float* b3   = (const float*)d_in[7];
    const float* mw1  = (const float*)d_in[8];
    const float* mb1  = (const float*)d_in[9];
    const float* mw2  = (const float*)d_in[10];
    const float* mb2  = (const float*)d_in[11];
    float* out = (float*)d_out;

    char* w = (char*)d_ws;
    size_t off = 0;
    auto carve = [&](size_t bytes) {
        void* p = w + off;
        off += (bytes + 255) & ~(size_t)255;
        return p;
    };
    u16* data_t   = (u16*)carve((size_t)BDIM * HDIM * WDIM * CDIM * 2);
    bf16r* xf     = (bf16r*)carve((size_t)MPAD * FIN * 2);
    bf16r* bt1    = (bf16r*)carve((size_t)MPAD * FIN * 2);
    bf16r* hm     = (bf16r*)carve((size_t)MPAD * 2048 * 2);
    bf16r* h2     = (bf16r*)carve((size_t)MPAD * 1024 * 2);
    bf16r* bt2    = (bf16r*)carve((size_t)1024 * 1024 * 2);
    bf16r* bt3    = (bf16r*)carve((size_t)128 * 1024 * 2);
    bf16r* bt4    = (bf16r*)carve((size_t)128 * 1024 * 2);
    float* offs   = (float*)carve((size_t)NROI * 98 * 4);
    float* maskb  = (float*)carve((size_t)NROI * 49 * 4);
    void*  P      = (void*)(w + off);
    size_t plane  = (size_t)MPAD * 2048 * 4;
    size_t avail  = (ws_size > off) ? ws_size - off : 0;
    int use256 = (avail >= 4 * plane);

    prep_kernel<<<42688, 256, 0, stream>>>(w1, mw1, w2, w3, mw2,
                                           bt1, bt2, bt3, bt4, data, data_t);
    pool1_kernel<<<dim3(NROI), 512, 0, stream>>>(data_t, rois, xf);

    if (use256) {
        gemm256_kernel<<<dim3(8, 8, 4), 512, 0, stream>>>(xf, FIN, bt1, FIN,
                                                          (bf16r*)P, 2048, 4, 196);
        reduce_kernel<<<4096, 256, 0, stream>>>(P, 11, 4, 1, b1, mb1, 1024,
                                                hm, 2048, NROI, 2048, 0);
    } else {
        gemm_mfma_kernel<<<dim3(16, 16, 3), 256, 0, stream>>>(xf, FIN, bt1, FIN,
                                                              (float*)P, 2048, 3);
        reduce_kernel<<<4096, 256, 0, stream>>>(P, 11, 3, 0, b1, mb1, 1024,
                                                hm, 2048, NROI, 2048, 0);
    }
    gemm2f_kernel<<<dim3(8, 16), 256, 0, stream>>>(hm, 2048, bt2, b2, h2);
    tailf_kernel<<<dim3(1, 32), 256, 0, stream>>>(h2, 1024, hm + 1024, 2048,
                                                  bt3, bt4, b3, mb2, offs, maskb);

    pool2_kernel<<<dim3(NROI, 2), 512, 0, stream>>>(data_t, rois, offs, maskb, out);
}

// Round 11
// 480.879 us; speedup vs baseline: 1.0531x; 1.0531x over previous
//
#include <hip/hip_runtime.h>
#include <math.h>

#define WDIM 128
#define HDIM 128
#define BDIM 4
#define CDIM 256
#define NROI 2000
#define MPAD 2048
#define FIN  12544   // 256*49
#define FC   1024
#define HWC  (HDIM * WDIM * CDIM)

typedef unsigned short bf16r;
typedef unsigned short u16;
typedef __attribute__((ext_vector_type(8))) short bf16x8;   // 8 bf16 = 4 VGPRs
typedef __attribute__((ext_vector_type(4))) float f32x4;
typedef __attribute__((ext_vector_type(8))) _Float16 half8;
typedef __attribute__((ext_vector_type(8))) unsigned short ushort8v;

__device__ __forceinline__ bf16r f2bf(float f) {
    unsigned u = __float_as_uint(f);
    u += 0x7FFFu + ((u >> 16) & 1u);
    return (bf16r)(u >> 16);
}
__device__ __forceinline__ float bf2f(bf16r h) {
    return __uint_as_float(((unsigned)h) << 16);
}
__device__ __forceinline__ u16 f2h(float f) {
    union { u16 s; _Float16 h; } c; c.h = (_Float16)f; return c.s;
}

__device__ __forceinline__ void async16(const bf16r* g, bf16r* l) {
    __builtin_amdgcn_global_load_lds(
        (const __attribute__((address_space(1))) unsigned int*)g,
        (__attribute__((address_space(3))) unsigned int*)l, 16, 0, 0);
}

#define VMW(n) asm volatile("s_waitcnt vmcnt(" #n ")" ::: "memory")
#define BARRIER() __builtin_amdgcn_s_barrier()

__device__ __forceinline__ void roi_geom(const float* __restrict__ rois, int n,
                                         int& b, float& sw, float& sh,
                                         float& rw, float& rh) {
    const float* r = rois + (size_t)n * 5;
    b = (int)r[0];
    float r1 = floorf(r[1] + 0.5f);
    float r2 = floorf(r[2] + 0.5f);
    float r3 = floorf(r[3] + 0.5f);
    float r4 = floorf(r[4] + 0.5f);
    sw = r1 * 0.0625f - 0.5f;
    sh = r2 * 0.0625f - 0.5f;
    float ew = (r3 + 1.0f) * 0.0625f - 0.5f;
    float eh = (r4 + 1.0f) * 0.0625f - 0.5f;
    rw = fmaxf(ew - sw, 0.1f);
    rh = fmaxf(eh - sh, 0.1f);
}

// ---- separable geometry phase --------------------------------------------
__device__ __forceinline__ void build_geometry(
        int n, int tid, const float* __restrict__ rois,
        const float* __restrict__ offs,      // null for pass 1
        const float* __restrict__ maskb,     // null for pass 1
        float* axW, unsigned* axMeta, uint2* wpix, int* npx, float* scale) {
    if (tid < 98) {
        int po = tid >> 1, axis = tid & 1;
        int b; float sw, sh, rw, rh;
        roi_geom(rois, n, b, sw, sh, rw, rh);
        float bw = rw * (1.f / 7.f), bh = rh * (1.f / 7.f);
        int ph = po / 7, pw = po - ph * 7;
        float start, sub;
        if (axis == 0) {
            start = (float)pw * bw + sw;
            if (offs) start += offs[(size_t)n * 98 + po] * 0.1f * rw;
            sub = bw * 0.25f;
        } else {
            start = (float)ph * bh + sh;
            if (offs) start += offs[(size_t)n * 98 + 49 + po] * 0.1f * rh;
            sub = bh * 0.25f;
        }
        float wsl[5] = {0.f, 0.f, 0.f, 0.f, 0.f};
        int base = 0, cnt = 0, mx = 0, any = 0;
#pragma unroll
        for (int i = 0; i < 4; ++i) {
            float p = start + (float)i * sub;
            bool valid = (p >= -0.5f) & (p <= 127.5f);
            float pc = fminf(fmaxf(p, 0.f), 127.f);
            int p0 = (int)floorf(pc);
            float d = pc - (float)p0;
            int p1 = min(p0 + 1, 127);
            if (valid) {
                if (!any) { base = p0; any = 1; }
                int c0 = p0 - base, c1 = p1 - base;
                float w0 = 1.f - d;
#pragma unroll
                for (int k = 0; k < 5; ++k)
                    wsl[k] += ((c0 == k) ? w0 : 0.f) + ((c1 == k) ? d : 0.f);
                cnt++;
                mx = max(mx, c1);
            }
        }
        int N = any ? mx + 1 : 0;
        axMeta[tid] = (unsigned)(N | (cnt << 3) | (base << 6));
#pragma unroll
        for (int k = 0; k < 5; ++k) axW[tid * 5 + k] = wsl[k];
    }
    __syncthreads();
    if (tid < 245) {
        int po = tid / 5, r = tid - po * 5;
        unsigned mx_ = axMeta[po * 2], my_ = axMeta[po * 2 + 1];
        int NX = mx_ & 7, NY = my_ & 7;
        int bx = (mx_ >> 6) & 127, by = (my_ >> 6) & 127;
        if (r == 0) {
            int cntx = (mx_ >> 3) & 7, cnty = (my_ >> 3) & 7;
            int ct = cntx * cnty;
            float sc = (ct > 0) ? 1.f / (float)ct : 0.f;
            if (maskb) sc *= (ct > 0) ? maskb[(size_t)n * 49 + po] : 0.f;
            npx[po] = NX * NY;
            scale[po] = sc;
        }
        if (r < NY) {
            float wyr = axW[(po * 2 + 1) * 5 + r];
            unsigned rowoff = (unsigned)(((by + r) * 128 + bx) * 512);  // bytes
#pragma unroll
            for (int c = 0; c < 5; ++c)
                if (c < NX)
                    wpix[po * 28 + r * NX + c] =
                        make_uint2(rowoff + (unsigned)c * 512u,
                                   __float_as_uint(wyr * axW[po * 2 * 5 + c]));
        }
    }
    __syncthreads();
}

// Fused prep, R11 wide-transaction tiling:
//  - weight transposes: 64x64 tiles. Reads 64 lanes x 4B = 256B/row;
//    writes ushort2 x 32 lanes = 128B/row (was 64B).
//  - data transpose: 64c x 32x tiles. Writes 64 lanes x 2B = 128B (was 64B).
// LDS t[64][65] f32; column re-reads are 2-way bank aliases (free).
__device__ __forceinline__ void conv_body64(const float* __restrict__ srcA,
                                            const float* __restrict__ srcB,
                                            int nsplit, int ncols, int Nout, int K,
                                            int kb, int nb, bf16r* __restrict__ dst,
                                            float (*t)[65], int tid) {
    int k0 = kb << 6, n0 = nb << 6;
    int tx = tid & 63, ty = tid >> 6;      // 4 k-rows per pass
#pragma unroll
    for (int i = 0; i < 64; i += 4) {
        int k = k0 + ty + i;
        int n = n0 + tx;
        const float* s = (n < nsplit) ? srcA : srcB;
        int col = (n < nsplit) ? n : n - nsplit;
        float v = (n < Nout && col < ncols) ? s[(size_t)k * ncols + col] : 0.f;
        t[ty + i][tx] = v;
    }
    __syncthreads();
    int tx2 = tid & 31, ty2 = tid >> 5;    // 8 n-rows per pass
#pragma unroll
    for (int i = 0; i < 64; i += 8) {
        int n = n0 + ty2 + i;
        if (n < Nout) {
            ushort2 o;
            o.x = f2bf(t[2 * tx2][ty2 + i]);
            o.y = f2bf(t[2 * tx2 + 1][ty2 + i]);
            *(ushort2*)(dst + (size_t)n * K + k0 + 2 * tx2) = o;
        }
    }
}

__global__ __launch_bounds__(256) void prep_kernel(
        const float* __restrict__ w1, const float* __restrict__ mw1,
        const float* __restrict__ w2, const float* __restrict__ w3,
        const float* __restrict__ mw2,
        bf16r* __restrict__ bt1, bf16r* __restrict__ bt2,
        bf16r* __restrict__ bt3, bf16r* __restrict__ bt4,
        const float* __restrict__ data, u16* __restrict__ data_t) {
    __shared__ float t[64][65];
    int tid = threadIdx.x;
    int blk = blockIdx.x;
    if (blk < 6272) {             // bt1: 196 k-tiles x 32 n-tiles
        conv_body64(w1, mw1, 1024, 1024, 2048, FIN, blk % 196, blk / 196, bt1, t, tid);
        return;
    }
    blk -= 6272;
    if (blk < 256) {              // bt2: 16 x 16
        conv_body64(w2, w2, 1 << 30, 1024, 1024, 1024, blk & 15, blk >> 4, bt2, t, tid);
        return;
    }
    blk -= 256;
    if (blk < 32) {               // bt3: 16 k-tiles x 2 n-tiles (N=98)
        conv_body64(w3, w3, 1 << 30, 98, 98, 1024, blk & 15, blk >> 4, bt3, t, tid);
        return;
    }
    blk -= 32;
    if (blk < 16) {               // bt4: 16 x 1 (N=49)
        conv_body64(mw2, mw2, 1 << 30, 49, 49, 1024, blk, 0, bt4, t, tid);
        return;
    }
    blk -= 16;
    {                             // data transpose: 4 xtile x 4 ctile x 512 (b,y)
        int x0 = (blk & 3) << 5;
        int c0 = ((blk >> 2) & 3) << 6;
        int bz = blk >> 4;
        int b = bz >> 7, y = bz & 127;
        int tx = tid & 31, ty = tid >> 5;      // 8 c-rows per pass
#pragma unroll
        for (int i = 0; i < 64; i += 8)
            t[ty + i][tx] = data[(((size_t)b * CDIM + c0 + ty + i) * HDIM + y) * WDIM + x0 + tx];
        __syncthreads();
        int tx2 = tid & 63, ty2 = tid >> 6;    // 4 x-rows per pass
#pragma unroll
        for (int i = 0; i < 32; i += 4)
            data_t[(((size_t)b * HDIM + y) * WDIM + x0 + ty2 + i) * CDIM + c0 + tx2] =
                f2h(t[tx2][ty2 + i]);
    }
}

// Pass-1 pooling: one block per ROI, 256 ch. Each 32-lane half owns one po;
// lane = 8 fp16 channels. Output xf in w1-natural k-order (k=c*49+po).
__global__ __launch_bounds__(512) void pool1_kernel(const u16* __restrict__ data_t,
                                                    const float* __restrict__ rois,
                                                    bf16r* __restrict__ xf) {
    __shared__ ushort tileX[49][264];   // 25,872 B
    __shared__ float axW[98 * 5];
    __shared__ unsigned axMeta[98];
    __shared__ uint2 wpix[49 * 28];
    __shared__ int npx[49];
    __shared__ float scale[49];
    int n = blockIdx.x, tid = threadIdx.x;
    build_geometry(n, tid, rois, nullptr, nullptr, axW, axMeta, wpix, npx, scale);
    int b = (int)rois[(size_t)n * 5];
    int wave = tid >> 6, lane = tid & 63, shalf = lane >> 5, c8 = (lane & 31) << 3;
    const char* dpb = (const char*)(data_t + (size_t)b * HWC + c8);
    for (int po = wave * 2 + shalf; po < 49; po += 16) {
        int npe = npx[po];
        float sc = scale[po];
        const uint2* wp = wpix + po * 28;
        float a[8];
#pragma unroll
        for (int k = 0; k < 8; ++k) a[k] = 0.f;
        int p = 0;
        for (; p + 2 <= npe; p += 2) {
            uint2 q0 = wp[p], q1 = wp[p + 1];
            half8 v0 = *(const half8*)(dpb + q0.x);
            half8 v1 = *(const half8*)(dpb + q1.x);
            float w0 = __uint_as_float(q0.y), w1 = __uint_as_float(q1.y);
#pragma unroll
            for (int k = 0; k < 8; ++k) a[k] += w0 * (float)v0[k];
#pragma unroll
            for (int k = 0; k < 8; ++k) a[k] += w1 * (float)v1[k];
        }
        if (p < npe) {
            uint2 q0 = wp[p];
            half8 v0 = *(const half8*)(dpb + q0.x);
            float w0 = __uint_as_float(q0.y);
#pragma unroll
            for (int k = 0; k < 8; ++k) a[k] += w0 * (float)v0[k];
        }
        ushort8v o;
#pragma unroll
        for (int k = 0; k < 8; ++k) o[k] = f2bf(a[k] * sc);
        *(ushort8v*)&tileX[po][c8] = o;
    }
    __syncthreads();
    bf16r* xp = xf + (size_t)n * FIN;
    for (int u = tid; u < 3136; u += 512) {
        int k0 = u << 2;
        ushort4 o;
#pragma unroll
        for (int j = 0; j < 4; ++j) {
            int k = k0 + j;
            int c = k / 49;
            int po = k - c * 49;
            ((ushort*)&o)[j] = tileX[po][c];
        }
        *(ushort4*)(xp + k0) = o;
    }
}

// Pass-2 pooling with offsets, times mask. 2 blocks/ROI (128 ch each),
// each 16-lane quarter owns one po. XOR-swizzled f32 LDS tile for the
// coalesced [c*49+po] writeout.
__global__ __launch_bounds__(512) void pool2_kernel(const u16* __restrict__ data_t,
                                                    const float* __restrict__ rois,
                                                    const float* __restrict__ offs,
                                                    const float* __restrict__ maskb,
                                                    float* __restrict__ out) {
    __shared__ float tile[49 * 128];   // 25,088 B
    __shared__ float axW[98 * 5];
    __shared__ unsigned axMeta[98];
    __shared__ uint2 wpix[49 * 28];
    __shared__ int npx[49];
    __shared__ float scale[49];
    int n = blockIdx.x, chalf = blockIdx.y, tid = threadIdx.x;
    build_geometry(n, tid, rois, offs, maskb, axW, axMeta, wpix, npx, scale);
    int b = (int)rois[(size_t)n * 5];
    int wave = tid >> 6, lane = tid & 63, q = lane >> 4, c8 = (lane & 15) << 3;
    const char* dpb = (const char*)(data_t + (size_t)b * HWC + chalf * 128 + c8);
    for (int po = wave * 4 + q; po < 49; po += 32) {
        int npe = npx[po];
        float sc = scale[po];
        const uint2* wp = wpix + po * 28;
        float a[8];
#pragma unroll
        for (int k = 0; k < 8; ++k) a[k] = 0.f;
        int p = 0;
        for (; p + 2 <= npe; p += 2) {
            uint2 q0 = wp[p], q1 = wp[p + 1];
            half8 v0 = *(const half8*)(dpb + q0.x);
            half8 v1 = *(const half8*)(dpb + q1.x);
            float w0 = __uint_as_float(q0.y), w1 = __uint_as_float(q1.y);
#pragma unroll
            for (int k = 0; k < 8; ++k) a[k] += w0 * (float)v0[k];
#pragma unroll
            for (int k = 0; k < 8; ++k) a[k] += w1 * (float)v1[k];
        }
        if (p < npe) {
            uint2 q0 = wp[p];
            half8 v0 = *(const half8*)(dpb + q0.x);
            float w0 = __uint_as_float(q0.y);
#pragma unroll
            for (int k = 0; k < 8; ++k) a[k] += w0 * (float)v0[k];
        }
        int cs = c8 ^ ((po & 7) << 3);
        float4 lo = make_float4(a[0] * sc, a[1] * sc, a[2] * sc, a[3] * sc);
        float4 hi = make_float4(a[4] * sc, a[5] * sc, a[6] * sc, a[7] * sc);
        *(float4*)&tile[po * 128 + cs] = lo;
        *(float4*)&tile[po * 128 + cs + 4] = hi;
    }
    __syncthreads();
    float* op = out + (size_t)n * FIN + (size_t)chalf * 6272;
    for (int i = tid; i < 6272; i += 512) {
        int c = i / 49, po = i - c * 49;
        op[i] = tile[po * 128 + (c ^ ((po & 7) << 3))];
    }
}

// =====================================================================
// 256x256 / BK=64 / 8-wave / 8-phase counted-vmcnt GEMM; bf16 partials.
// Register-persistent fragments; R4-verified schedule. ktiles = K/64.
// =====================================================================
#define STAGE_A(buf, h, kt) do { \
    async16(Abase + (size_t)(kt) * 64 + sAoff[h][0], &lds[buf][0][((h) * 128 + wave * 8) * 64]); \
    async16(Abase + (size_t)(kt) * 64 + sAoff[h][1], &lds[buf][0][((h) * 128 + 64 + wave * 8) * 64]); \
} while (0)
#define STAGE_B(buf, h, kt) do { \
    async16(Bbase + (size_t)(kt) * 64 + sBoff[h][0], &lds[buf][1][((h) * 128 + wave * 8) * 64]); \
    async16(Bbase + (size_t)(kt) * 64 + sBoff[h][1], &lds[buf][1][((h) * 128 + 64 + wave * 8) * 64]); \
} while (0)
#define LDA_HALF(buf, mh) do { \
    const char* Ar = (const char*)&lds[buf][0][0] + aQ + (mh) * 16384; \
    _Pragma("unroll") for (int i = 0; i < 4; ++i) \
        _Pragma("unroll") for (int ks = 0; ks < 2; ++ks) \
            aF[i][ks] = *(const bf16x8*)(Ar + i * 2048 + fRB[ks]); \
} while (0)
#define LDB_HALF(dst, buf, nh) do { \
    const char* Br = (const char*)&lds[buf][1][0] + bQ + (nh) * 16384; \
    _Pragma("unroll") for (int jf = 0; jf < 2; ++jf) \
        _Pragma("unroll") for (int ks = 0; ks < 2; ++ks) \
            dst[jf][ks] = *(const bf16x8*)(Br + jf * 2048 + fRB[ks]); \
} while (0)
#define MMA_Q(mh, nh, B) do { \
    __builtin_amdgcn_s_setprio(1); \
    _Pragma("unroll") for (int i = 0; i < 4; ++i) \
        _Pragma("unroll") for (int jf = 0; jf < 2; ++jf) \
            _Pragma("unroll") for (int ks = 0; ks < 2; ++ks) \
                acc[(mh) * 4 + i][(nh) * 2 + jf] = __builtin_amdgcn_mfma_f32_16x16x32_bf16( \
                    aF[i][ks], B[jf][ks], acc[(mh) * 4 + i][(nh) * 2 + jf], 0, 0, 0); \
    __builtin_amdgcn_s_setprio(0); \
} while (0)

__global__ __launch_bounds__(512, 2) void gemm256_kernel(
        const bf16r* __restrict__ A, int lda,
        const bf16r* __restrict__ Bt, int ldb,
        bf16r* __restrict__ P, int Npad, int KS, int ktiles) {
    __shared__ bf16r lds[2][2][256 * 64];   // 128 KiB
    int tid = threadIdx.x;
    int wave = tid >> 6, lane = tid & 63;
    int l15 = lane & 15, quad = lane >> 4;
    int wm = wave >> 2, wn = wave & 3;

    // within-z bijective XCD swizzle (gridDim.x*gridDim.y % 8 == 0)
    int idx = blockIdx.x + gridDim.x * blockIdx.y;
    int nid = (idx & 7) * ((gridDim.x * gridDim.y) >> 3) + (idx >> 3);
    int bx = nid % gridDim.x, by = nid / gridDim.x;
    int m0 = by << 8, n0 = bx << 8;
    int z = blockIdx.z;

    // staging source offsets (pre-swizzled granule)
    int sAoff[2][2], sBoff[2][2];
#pragma unroll
    for (int h = 0; h < 2; ++h)
#pragma unroll
        for (int j = 0; j < 2; ++j) {
            int slot = h * 128 + j * 64 + wave * 8 + (lane >> 3);
            int g = (lane & 7) ^ ((slot >> 1) & 7);
            int rowA = ((slot >> 6) & 1) * 128 + (slot >> 7) * 64 + (slot & 63);
            int colB = ((slot >> 5) & 3) * 64 + (slot >> 7) * 32 + (slot & 31);
            sAoff[h][j] = rowA * lda + g * 8;
            sBoff[h][j] = colB * ldb + g * 8;
        }
    const bf16r* Abase = A + (size_t)m0 * lda;
    const bf16r* Bbase = Bt + (size_t)n0 * ldb;

    // frag-read per-lane byte bases (granule XOR keyed on l15 bits [3:1])
    int fRB[2];
#pragma unroll
    for (int ks = 0; ks < 2; ++ks)
        fRB[ks] = l15 * 128 + ((((ks << 2) + quad) ^ ((l15 >> 1) & 7)) << 4);
    int aQ = wm * 8192;    // wm*64 slots * 128 B
    int bQ = wn * 4096;    // wn*32 slots * 128 B

    f32x4 acc[8][4];
#pragma unroll
    for (int i = 0; i < 8; ++i)
#pragma unroll
        for (int j = 0; j < 4; ++j) acc[i][j] = (f32x4){0.f, 0.f, 0.f, 0.f};
    bf16x8 aF[4][2], bF0[2][2], bF1[2][2];

    int tb = ((ktiles * z) / KS) & ~1;
    int te = (z == KS - 1) ? ktiles : ((ktiles * (z + 1)) / KS) & ~1;
    int nit = (te - tb) >> 1;

    // prologue: tile tb fully into buf0; tile tb+1 halves A0,B0 into buf1
    STAGE_A(0, 0, tb); STAGE_B(0, 0, tb); STAGE_A(0, 1, tb); STAGE_B(0, 1, tb);
    STAGE_A(1, 0, tb + 1); STAGE_B(1, 0, tb + 1);
    VMW(4);
    BARRIER();

    for (int it = 0; it < nit; ++it) {
        int t1 = tb + 2 * it + 1, nx0 = t1 + 1, nx1 = t1 + 2;
        bool last = (it == nit - 1);
        // ---- buf0 (K-tile 2t): quadrants (0,0)(0,1)(1,1)(1,0) ----
        LDA_HALF(0, 0); LDB_HALF(bF0, 0, 0);
        STAGE_A(1, 1, t1);
        BARRIER();
        MMA_Q(0, 0, bF0);
        BARRIER();

        LDB_HALF(bF1, 0, 1);
        STAGE_B(1, 1, t1);
        BARRIER();
        MMA_Q(0, 1, bF1);
        BARRIER();

        LDA_HALF(0, 1);
        if (!last) STAGE_A(0, 0, nx0);
        BARRIER();
        MMA_Q(1, 1, bF1);
        BARRIER();

        if (!last) STAGE_B(0, 0, nx0);
        BARRIER();
        MMA_Q(1, 0, bF0);
        if (last) { VMW(0); } else { VMW(4); }
        BARRIER();

        // ---- buf1 (K-tile 2t+1) ----
        LDA_HALF(1, 0); LDB_HALF(bF0, 1, 0);
        if (!last) STAGE_A(0, 1, nx0);
        BARRIER();
        MMA_Q(0, 0, bF0);
        BARRIER();

        LDB_HALF(bF1, 1, 1);
        if (!last) STAGE_B(0, 1, nx0);
        BARRIER();
        MMA_Q(0, 1, bF1);
        BARRIER();

        LDA_HALF(1, 1);
        if (!last) STAGE_A(1, 0, nx1);
        BARRIER();
        MMA_Q(1, 1, bF1);
        BARRIER();

        if (!last) STAGE_B(1, 0, nx1);
        BARRIER();
        MMA_Q(1, 0, bF0);
        if (!last) { VMW(4); }
        BARRIER();
    }

    bf16r* Pp = P + (size_t)z * MPAD * Npad;
#pragma unroll
    for (int I = 0; I < 8; ++I) {
        int row = m0 + wm * 128 + I * 16 + quad * 4;
#pragma unroll
        for (int J = 0; J < 4; ++J) {
            int col = n0 + wn * 64 + J * 16 + l15;
            bf16r* o = Pp + (size_t)row * Npad + col;
#pragma unroll
            for (int r = 0; r < 4; ++r) o[(size_t)r * Npad] = f2bf(acc[I][J][r]);
        }
    }
}

// MFMA bf16 GEMM (128x128 2-barrier, split-K, f32 partials).
__global__ __launch_bounds__(256) void gemm_mfma_kernel(
        const bf16r* __restrict__ A, int lda,
        const bf16r* __restrict__ Bt, int K,
        float* __restrict__ P, int Npad, int KS) {
    __shared__ bf16r As[128 * 32];
    __shared__ bf16r Bs[128 * 32];
    int tid = threadIdx.x;
    int wave = tid >> 6, lane = tid & 63;
    int nwgxy = gridDim.x * gridDim.y;
    int idx = blockIdx.x + gridDim.x * blockIdx.y;
    int chunk = nwgxy >> 3;
    int nid = (idx & 7) * chunk + (idx >> 3);
    int bx = nid % gridDim.x, by = nid / gridDim.x;
    int m0 = by << 7, n0 = bx << 7;
    int z = blockIdx.z;

    int srow = lane >> 2;
    int kchunk = ((lane & 3) ^ ((lane >> 3) & 3)) << 3;
    const bf16r* aG0 = A + (size_t)(m0 + wave * 32 + srow) * lda + kchunk;
    const bf16r* aG1 = A + (size_t)(m0 + wave * 32 + 16 + srow) * lda + kchunk;
    const bf16r* bG0 = Bt + (size_t)(n0 + wave * 32 + srow) * K + kchunk;
    const bf16r* bG1 = Bt + (size_t)(n0 + wave * 32 + 16 + srow) * K + kchunk;
    bf16r* aL0 = As + wave * 1024;
    bf16r* aL1 = As + wave * 1024 + 512;
    bf16r* bL0 = Bs + wave * 1024;
    bf16r* bL1 = Bs + wave * 1024 + 512;

    int l15 = lane & 15, quad = lane >> 4;
    int wr = wave >> 1, wc = wave & 1;
    int psw = (quad ^ ((l15 >> 1) & 3)) << 3;
    int aoff[4], boff[4];
#pragma unroll
    for (int t = 0; t < 4; ++t) {
        aoff[t] = ((wr * 64 + t * 16 + l15) * 32 + psw) * 2;
        boff[t] = ((wc * 64 + t * 16 + l15) * 32 + psw) * 2;
    }

    f32x4 acc[4][4];
#pragma unroll
    for (int i = 0; i < 4; ++i)
#pragma unroll
        for (int j = 0; j < 4; ++j) acc[i][j] = (f32x4){0.f, 0.f, 0.f, 0.f};

    int iters = K >> 5;
    int i0 = (int)((long)iters * z / KS);
    int i1 = (int)((long)iters * (z + 1) / KS);

    {
        size_t k0 = (size_t)i0 << 5;
        async16(aG0 + k0, aL0); async16(aG1 + k0, aL1);
        async16(bG0 + k0, bL0); async16(bG1 + k0, bL1);
    }
    for (int it = i0; it < i1; ++it) {
        __syncthreads();
        bf16x8 af[4], bfv[4];
#pragma unroll
        for (int t = 0; t < 4; ++t) af[t] = *(const bf16x8*)((const char*)As + aoff[t]);
#pragma unroll
        for (int t = 0; t < 4; ++t) bfv[t] = *(const bf16x8*)((const char*)Bs + boff[t]);
        __syncthreads();
        if (it + 1 < i1) {
            size_t k0 = (size_t)(it + 1) << 5;
            async16(aG0 + k0, aL0); async16(aG1 + k0, aL1);
            async16(bG0 + k0, bL0); async16(bG1 + k0, bL1);
        }
#pragma unroll
        for (int i = 0; i < 4; ++i)
#pragma unroll
            for (int j = 0; j < 4; ++j)
                acc[i][j] = __builtin_amdgcn_mfma_f32_16x16x32_bf16(af[i], bfv[j], acc[i][j], 0, 0, 0);
    }

    float* Pp = P + (size_t)z * MPAD * Npad;
#pragma unroll
    for (int i = 0; i < 4; ++i) {
        int row = m0 + wr * 64 + i * 16 + quad * 4;
#pragma unroll
        for (int j = 0; j < 4; ++j) {
            int col = n0 + wc * 64 + j * 16 + l15;
            float* o = Pp + (size_t)row * Npad + col;
#pragma unroll
            for (int r = 0; r < 4; ++r) o[(size_t)r * Npad] = acc[i][j][r];
        }
    }
}

// Fused tail GEMMs (split-K kept for parallelism): prob0 = offs pre-act
// (A=h2, Bt=bt3), prob1 = mask pre-act (A=hm+1024, Bt=bt4). N=128 padded,
// K=1024, KS=8. Partials: prob p plane z at P + (p*8+z)*MPAD*128.
__global__ __launch_bounds__(256) void gemm_tail_kernel(
        const bf16r* __restrict__ A0, int lda0,
        const bf16r* __restrict__ A1, int lda1,
        const bf16r* __restrict__ Bt0, const bf16r* __restrict__ Bt1,
        float* __restrict__ P) {
    __shared__ bf16r As[128 * 32];
    __shared__ bf16r Bs[128 * 32];
    int tid = threadIdx.x;
    int wave = tid >> 6, lane = tid & 63;
    int prob = blockIdx.y >> 4;
    int m0 = (blockIdx.y & 15) << 7;
    const bf16r* A = prob ? A1 : A0;
    int lda = prob ? lda1 : lda0;
    const bf16r* Bt = prob ? Bt1 : Bt0;
    int z = blockIdx.z;
    const int K = 1024, KS = 8, Npad = 128;

    int srow = lane >> 2;
    int kchunk = ((lane & 3) ^ ((lane >> 3) & 3)) << 3;
    const bf16r* aG0 = A + (size_t)(m0 + wave * 32 + srow) * lda + kchunk;
    const bf16r* aG1 = A + (size_t)(m0 + wave * 32 + 16 + srow) * lda + kchunk;
    const bf16r* bG0 = Bt + (size_t)(wave * 32 + srow) * K + kchunk;
    const bf16r* bG1 = Bt + (size_t)(wave * 32 + 16 + srow) * K + kchunk;
    bf16r* aL0 = As + wave * 1024;
    bf16r* aL1 = As + wave * 1024 + 512;
    bf16r* bL0 = Bs + wave * 1024;
    bf16r* bL1 = Bs + wave * 1024 + 512;

    int l15 = lane & 15, quad = lane >> 4;
    int wr = wave >> 1, wc = wave & 1;
    int psw = (quad ^ ((l15 >> 1) & 3)) << 3;
    int aoff[4], boff[4];
#pragma unroll
    for (int t = 0; t < 4; ++t) {
        aoff[t] = ((wr * 64 + t * 16 + l15) * 32 + psw) * 2;
        boff[t] = ((wc * 64 + t * 16 + l15) * 32 + psw) * 2;
    }

    f32x4 acc[4][4];
#pragma unroll
    for (int i = 0; i < 4; ++i)
#pragma unroll
        for (int j = 0; j < 4; ++j) acc[i][j] = (f32x4){0.f, 0.f, 0.f, 0.f};

    int iters = K >> 5;
    int i0 = iters * z / KS;
    int i1 = iters * (z + 1) / KS;

    {
        size_t k0 = (size_t)i0 << 5;
        async16(aG0 + k0, aL0); async16(aG1 + k0, aL1);
        async16(bG0 + k0, bL0); async16(bG1 + k0, bL1);
    }
    for (int it = i0; it < i1; ++it) {
        __syncthreads();
        bf16x8 af[4], bfv[4];
#pragma unroll
        for (int t = 0; t < 4; ++t) af[t] = *(const bf16x8*)((const char*)As + aoff[t]);
#pragma unroll
        for (int t = 0; t < 4; ++t) bfv[t] = *(const bf16x8*)((const char*)Bs + boff[t]);
        __syncthreads();
        if (it + 1 < i1) {
            size_t k0 = (size_t)(it + 1) << 5;
            async16(aG0 + k0, aL0); async16(aG1 + k0, aL1);
            async16(bG0 + k0, bL0); async16(bG1 + k0, bL1);
        }
#pragma unroll
        for (int i = 0; i < 4; ++i)
#pragma unroll
            for (int j = 0; j < 4; ++j)
                acc[i][j] = __builtin_amdgcn_mfma_f32_16x16x32_bf16(af[i], bfv[j], acc[i][j], 0, 0, 0);
    }

    float* Pp = P + (size_t)(prob * 8 + z) * (MPAD * 128);
#pragma unroll
    for (int i = 0; i < 4; ++i) {
        int row = m0 + wr * 64 + i * 16 + quad * 4;
#pragma unroll
        for (int j = 0; j < 4; ++j) {
            int col = wc * 64 + j * 16 + l15;
            float* o = Pp + (size_t)row * Npad + col;
#pragma unroll
            for (int r = 0; r < 4; ++r) o[(size_t)r * Npad] = acc[i][j][r];
        }
    }
}

// sum split-K partials + bias + activation + dtype convert (float4/thread).
// pbf16: partials stored as bf16 (gemm256 path).
__global__ __launch_bounds__(256) void reduce_kernel(
        const void* __restrict__ Pv, int shift, int KS, int pbf16,
        const float* __restrict__ bias0, const float* __restrict__ bias1, int bsplit,
        void* __restrict__ Out, int ldo, int M, int Nreal, int outmode) {
    int idx = (blockIdx.x * 256 + threadIdx.x) << 2;
    int Npad = 1 << shift;
    int row = idx >> shift, col = idx & (Npad - 1);
    f32x4 s = (f32x4){0.f, 0.f, 0.f, 0.f};
    size_t plane = (size_t)MPAD << shift;
    if (pbf16) {
        const bf16r* P = (const bf16r*)Pv;
        for (int zz = 0; zz < KS; ++zz) {
            ushort4 u = *(const ushort4*)(P + (size_t)zz * plane + idx);
            s[0] += bf2f(u.x); s[1] += bf2f(u.y); s[2] += bf2f(u.z); s[3] += bf2f(u.w);
        }
    } else {
        const float* P = (const float*)Pv;
        for (int zz = 0; zz < KS; ++zz) s += *(const f32x4*)(P + (size_t)zz * plane + idx);
    }
    if (row < M) {
#pragma unroll
        for (int e = 0; e < 4; ++e) {
            int c = col + e;
            if (c < Nreal) {
                float b = (c < bsplit) ? bias0[c] : bias1[c - bsplit];
                float v = s[e] + b;
                if (outmode == 0) {
                    v = fmaxf(v, 0.f);
                    ((bf16r*)Out)[(size_t)row * ldo + c] = f2bf(v);
                } else {
                    if (outmode == 2) v = 1.f / (1.f + expf(-v));
                    ((float*)Out)[(size_t)row * ldo + c] = v;
                }
            }
        }
    }
}

// fused reduce for both tail GEMMs: blocks [0,256) -> offs (linear),
// blocks [256,512) -> mask (sigmoid).
__global__ __launch_bounds__(256) void reduce34_kernel(
        const float* __restrict__ P, const float* __restrict__ b3,
        const float* __restrict__ mb2, float* __restrict__ offs,
        float* __restrict__ maskb) {
    int blk = blockIdx.x;
    int prob = blk >> 8;
    int idx = ((blk & 255) * 256 + threadIdx.x) << 2;
    int row = idx >> 7, col = idx & 127;
    f32x4 s = (f32x4){0.f, 0.f, 0.f, 0.f};
    size_t plane = (size_t)MPAD * 128;
    const float* Pb = P + (size_t)(prob * 8) * plane;
    for (int zz = 0; zz < 8; ++zz) s += *(const f32x4*)(Pb + (size_t)zz * plane + idx);
    if (row < NROI) {
        if (prob == 0) {
#pragma unroll
            for (int e = 0; e < 4; ++e) {
                int c = col + e;
                if (c < 98) offs[(size_t)row * 98 + c] = s[e] + b3[c];
            }
        } else {
#pragma unroll
            for (int e = 0; e < 4; ++e) {
                int c = col + e;
                if (c < 49) maskb[(size_t)row * 49 + c] = 1.f / (1.f + expf(-(s[e] + mb2[c])));
            }
        }
    }
}

extern "C" void kernel_launch(void* const* d_in, const int* in_sizes, int n_in,
                              void* d_out, int out_size, void* d_ws, size_t ws_size,
                              hipStream_t stream) {
    const float* data = (const float*)d_in[0];
    const float* rois = (const float*)d_in[1];
    const float* w1   = (const float*)d_in[2];
    const float* b1   = (const float*)d_in[3];
    const float* w2   = (const float*)d_in[4];
    const float* b2   = (const float*)d_in[5];
    const float* w3   = (const float*)d_in[6];
    const float* b3   = (const float*)d_in[7];
    const float* mw1  = (const float*)d_in[8];
    const float* mb1  = (const float*)d_in[9];
    const float* mw2  = (const float*)d_in[10];
    const float* mb2  = (const float*)d_in[11];
    float* out = (float*)d_out;

    char* w = (char*)d_ws;
    size_t off = 0;
    auto carve = [&](size_t bytes) {
        void* p = w + off;
        off += (bytes + 255) & ~(size_t)255;
        return p;
    };
    u16* data_t   = (u16*)carve((size_t)BDIM * HDIM * WDIM * CDIM * 2);
    bf16r* xf     = (bf16r*)carve((size_t)MPAD * FIN * 2);
    bf16r* bt1    = (bf16r*)carve((size_t)MPAD * FIN * 2);
    bf16r* hm     = (bf16r*)carve((size_t)MPAD * 2048 * 2);
    bf16r* h2     = (bf16r*)carve((size_t)MPAD * 1024 * 2);
    bf16r* bt2    = (bf16r*)carve((size_t)1024 * 1024 * 2);
    bf16r* bt3    = (bf16r*)carve((size_t)128 * 1024 * 2);
    bf16r* bt4    = (bf16r*)carve((size_t)128 * 1024 * 2);
    float* offs   = (float*)carve((size_t)NROI * 98 * 4);
    float* maskb  = (float*)carve((size_t)NROI * 49 * 4);
    void*  P      = (void*)(w + off);
    size_t plane  = (size_t)MPAD * 2048 * 4;
    size_t avail  = (ws_size > off) ? ws_size - off : 0;
    int use256 = (avail >= 4 * plane);

    prep_kernel<<<14768, 256, 0, stream>>>(w1, mw1, w2, w3, mw2,
                                           bt1, bt2, bt3, bt4, data, data_t);
    pool1_kernel<<<dim3(NROI), 512, 0, stream>>>(data_t, rois, xf);

    if (use256) {
        gemm256_kernel<<<dim3(8, 8, 4), 512, 0, stream>>>(xf, FIN, bt1, FIN,
                                                          (bf16r*)P, 2048, 4, 196);
        reduce_kernel<<<4096, 256, 0, stream>>>(P, 11, 4, 1, b1, mb1, 1024,
                                                hm, 2048, NROI, 2048, 0);
    } else {
        gemm_mfma_kernel<<<dim3(16, 16, 3), 256, 0, stream>>>(xf, FIN, bt1, FIN,
                                                              (float*)P, 2048, 3);
        reduce_kernel<<<4096, 256, 0, stream>>>(P, 11, 3, 0, b1, mb1, 1024,
                                                hm, 2048, NROI, 2048, 0);
    }
    gemm_mfma_kernel<<<dim3(8, 16, 4), 256, 0, stream>>>(hm, 2048, bt2, 1024,
                                                         (float*)P, 1024, 4);
    reduce_kernel<<<2048, 256, 0, stream>>>(P, 10, 4, 0, b2, b2, 1 << 30,
                                            h2, 1024, NROI, 1024, 0);
    gemm_tail_kernel<<<dim3(1, 32, 8), 256, 0, stream>>>(h2, 1024, hm + 1024, 2048,
                                                         bt3, bt4, (float*)P);
    reduce34_kernel<<<512, 256, 0, stream>>>((const float*)P, b3, mb2, offs, maskb);

    pool2_kernel<<<dim3(NROI, 2), 512, 0, stream>>>(data_t, rois, offs, maskb, out);
}